// Round 14
// baseline (47.648 us; speedup 1.0000x reference)
//
#include <hip/hip_runtime.h>

typedef float  f32x4  __attribute__((ext_vector_type(4)));
typedef short  bf16x4 __attribute__((ext_vector_type(4)));
typedef short  bf16x8 __attribute__((ext_vector_type(8)));

// Problem dims (fixed by reference): bs=4, L=512, H=768, C=48
#define H_DIM 768
#define C_DIM 48
#define NROWS 2048          // bs * L
#define TWO_H 1536

// MFMA gemm geometry: 256 blocks = 128 rowgroups x 2 halves; 4 waves/block.
#define GBM 16              // rows per block
#define AST 392             // padded bf16 row stride
#define MT_LD 52            // merge tile row stride (f32)

__device__ __forceinline__ unsigned short f2bf(float f) {   // RNE f32->bf16
    unsigned x = __float_as_uint(f);
    return (unsigned short)((x + 0x7fffu + ((x >> 16) & 1u)) >> 16);
}

// ---------------------------------------------------------------------------
// Kernel 1: proj GEMM via MFMA (bf16 inputs, f32 accum), R13 +
// register-prefetch of the second K-half (one global-latency exposure).
//   block(rg, half): rows rg*16..+16, cols half*48..+48; 256 thr = 4 waves.
//   Per half: A[16][384]+B[48][384] bf16 in LDS (50.2 KB); wave w covers
//   k in [w*96, w*96+96): 3 k-steps x 3 col-tiles = 9 mfma_f32_16x16x32_bf16.
//   Frag k-mapping: k = 4*(lane>>4) + (j&3) + 16*(j>>2); C/D per m89.
// ---------------------------------------------------------------------------
__global__ __launch_bounds__(256) void gemm_kernel(const float* __restrict__ hs,
                                                   const float* __restrict__ W,
                                                   float* __restrict__ proj) {
    __shared__ __align__(16) char smem[50176];
    unsigned short* Ab = (unsigned short*)smem;           // [16][392] bf16
    unsigned short* Bb = Ab + GBM * AST;                  // [48][392] bf16
    float*          mt = (float*)smem;                    // [4][16][52] f32 (aliased)

    const int t    = threadIdx.x;
    const int half = blockIdx.x & 1;
    const int rg   = blockIdx.x >> 1;                     // 0..127
    const int row0 = rg * GBM;

    const int w    = t >> 6;                              // wave 0..3
    const int lane = t & 63;
    const int g    = lane >> 4;                           // 0..3
    const int m    = lane & 15;                           // 0..15

    const f32x4* __restrict__ hs4 = reinterpret_cast<const f32x4*>(hs);
    const f32x4* __restrict__ Wv4 = reinterpret_cast<const f32x4*>(W);

    // Per-thread staging indices (constant across halves).
    int a_row[6], a_kf4[6], b_c[18], b_kf4[18];
    #pragma unroll
    for (int q = 0; q < 6; ++q) {
        const int idx = q * 256 + t;
        a_row[q] = idx / 96;  a_kf4[q] = idx % 96;
    }
    #pragma unroll
    for (int q = 0; q < 18; ++q) {
        const int idx = q * 256 + t;
        b_c[q] = idx / 96;    b_kf4[q] = idx % 96;
    }

    f32x4 acc[3];
    #pragma unroll
    for (int tc = 0; tc < 3; ++tc) acc[tc] = (f32x4){0.f, 0.f, 0.f, 0.f};

    f32x4 av[6], bv[18];

    // ---- load half 0 into regs; cvt+write to LDS ----
    #pragma unroll
    for (int q = 0; q < 6; ++q)
        av[q] = hs4[(size_t)(row0 + a_row[q]) * 192 + a_kf4[q]];
    #pragma unroll
    for (int q = 0; q < 18; ++q)
        bv[q] = Wv4[(size_t)b_c[q] * 384 + half * 192 + b_kf4[q]];
    #pragma unroll
    for (int q = 0; q < 6; ++q) {
        bf16x4 p = {(short)f2bf(av[q].x), (short)f2bf(av[q].y),
                    (short)f2bf(av[q].z), (short)f2bf(av[q].w)};
        *reinterpret_cast<bf16x4*>(Ab + a_row[q] * AST + a_kf4[q] * 4) = p;
    }
    #pragma unroll
    for (int q = 0; q < 18; ++q) {
        bf16x4 p = {(short)f2bf(bv[q].x), (short)f2bf(bv[q].y),
                    (short)f2bf(bv[q].z), (short)f2bf(bv[q].w)};
        *reinterpret_cast<bf16x4*>(Bb + b_c[q] * AST + b_kf4[q] * 4) = p;
    }
    __syncthreads();

    // ---- issue half-1 loads NOW (hide latency under half-0 MFMAs) ----
    #pragma unroll
    for (int q = 0; q < 6; ++q)
        av[q] = hs4[(size_t)(row0 + a_row[q]) * 192 + 96 + a_kf4[q]];
    #pragma unroll
    for (int q = 0; q < 18; ++q)
        bv[q] = Wv4[(size_t)b_c[q] * 384 + half * 192 + 96 + b_kf4[q]];

    // ---- compute half 0 ----
    #pragma unroll
    for (int ks = 0; ks < 3; ++ks) {
        const int klo = w * 96 + ks * 32 + 4 * g;
        const bf16x4 alo = *reinterpret_cast<const bf16x4*>(Ab + m * AST + klo);
        const bf16x4 ahi = *reinterpret_cast<const bf16x4*>(Ab + m * AST + klo + 16);
        bf16x8 af;
        #pragma unroll
        for (int i = 0; i < 4; ++i) { af[i] = alo[i]; af[i + 4] = ahi[i]; }
        #pragma unroll
        for (int tc = 0; tc < 3; ++tc) {
            const unsigned short* bp = Bb + (tc * 16 + m) * AST + klo;
            const bf16x4 blo = *reinterpret_cast<const bf16x4*>(bp);
            const bf16x4 bhi = *reinterpret_cast<const bf16x4*>(bp + 16);
            bf16x8 bfr;
            #pragma unroll
            for (int i = 0; i < 4; ++i) { bfr[i] = blo[i]; bfr[i + 4] = bhi[i]; }
            acc[tc] = __builtin_amdgcn_mfma_f32_16x16x32_bf16(af, bfr, acc[tc], 0, 0, 0);
        }
    }
    __syncthreads();   // everyone done reading LDS half 0

    // ---- cvt+write half 1 (loads already in flight) ----
    #pragma unroll
    for (int q = 0; q < 6; ++q) {
        bf16x4 p = {(short)f2bf(av[q].x), (short)f2bf(av[q].y),
                    (short)f2bf(av[q].z), (short)f2bf(av[q].w)};
        *reinterpret_cast<bf16x4*>(Ab + a_row[q] * AST + a_kf4[q] * 4) = p;
    }
    #pragma unroll
    for (int q = 0; q < 18; ++q) {
        bf16x4 p = {(short)f2bf(bv[q].x), (short)f2bf(bv[q].y),
                    (short)f2bf(bv[q].z), (short)f2bf(bv[q].w)};
        *reinterpret_cast<bf16x4*>(Bb + b_c[q] * AST + b_kf4[q] * 4) = p;
    }
    __syncthreads();

    // ---- compute half 1 ----
    #pragma unroll
    for (int ks = 0; ks < 3; ++ks) {
        const int klo = w * 96 + ks * 32 + 4 * g;
        const bf16x4 alo = *reinterpret_cast<const bf16x4*>(Ab + m * AST + klo);
        const bf16x4 ahi = *reinterpret_cast<const bf16x4*>(Ab + m * AST + klo + 16);
        bf16x8 af;
        #pragma unroll
        for (int i = 0; i < 4; ++i) { af[i] = alo[i]; af[i + 4] = ahi[i]; }
        #pragma unroll
        for (int tc = 0; tc < 3; ++tc) {
            const unsigned short* bp = Bb + (tc * 16 + m) * AST + klo;
            const bf16x4 blo = *reinterpret_cast<const bf16x4*>(bp);
            const bf16x4 bhi = *reinterpret_cast<const bf16x4*>(bp + 16);
            bf16x8 bfr;
            #pragma unroll
            for (int i = 0; i < 4; ++i) { bfr[i] = blo[i]; bfr[i + 4] = bhi[i]; }
            acc[tc] = __builtin_amdgcn_mfma_f32_16x16x32_bf16(af, bfr, acc[tc], 0, 0, 0);
        }
    }

    // ---- merge 4 waves' k-partials (mt aliases A/B; all reads done) ----
    __syncthreads();
    #pragma unroll
    for (int tc = 0; tc < 3; ++tc)
        #pragma unroll
        for (int r = 0; r < 4; ++r)
            mt[w * (GBM * MT_LD) + (g * 4 + r) * MT_LD + tc * 16 + m] = acc[tc][r];
    __syncthreads();

    if (t < GBM * 12) {                                   // 192 f32x4 outputs
        const int row = t / 12;
        const int c4  = t % 12;
        f32x4 s = *reinterpret_cast<const f32x4*>(mt + row * MT_LD + c4 * 4);
        #pragma unroll
        for (int ww = 1; ww < 4; ++ww)
            s += *reinterpret_cast<const f32x4*>(mt + ww * (GBM * MT_LD) + row * MT_LD + c4 * 4);
        reinterpret_cast<f32x4*>(proj)[(size_t)half * (NROWS * 12)
                                       + (size_t)(row0 + row) * 12 + c4] = s;
    }
}

// ---------------------------------------------------------------------------
// Kernel 2: out[b,i,j,c] = proj_i[b,i,c] + proj_j[b,j,c] + bias[c]
// R4 structure + nontemporal stores (output lines are never re-read).
// ---------------------------------------------------------------------------
__global__ __launch_bounds__(256) void bcast_kernel(const float* __restrict__ proj,
                                                    const float* __restrict__ bias,
                                                    float* __restrict__ out) {
    const int gi = blockIdx.x;          // b*512 + i
    const int b  = gi >> 9;

    __shared__ f32x4 rowi[C_DIM / 4];   // proj_i[b,i,:] + bias  (12 f32x4)

    const int t = threadIdx.x;
    if (t < C_DIM / 4) {
        f32x4 pi = reinterpret_cast<const f32x4*>(proj + (size_t)gi * C_DIM)[t];
        f32x4 bb = reinterpret_cast<const f32x4*>(bias)[t];
        rowi[t] = pi + bb;
    }
    __syncthreads();

    const f32x4* __restrict__ pj =
        reinterpret_cast<const f32x4*>(proj + (size_t)NROWS * C_DIM
                                            + (size_t)b * 512 * C_DIM);
    f32x4* __restrict__ o =
        reinterpret_cast<f32x4*>(out) + (size_t)gi * 6144;

    #pragma unroll
    for (int it = 0; it < 24; ++it) {
        const int p = it * 256 + t;
        f32x4 v = pj[p] + rowi[p % 12];
        __builtin_nontemporal_store(v, &o[p]);
    }
}

extern "C" void kernel_launch(void* const* d_in, const int* in_sizes, int n_in,
                              void* d_out, int out_size, void* d_ws, size_t ws_size,
                              hipStream_t stream) {
    const float* hs   = (const float*)d_in[0];   // (4, 512, 768) f32
    const float* W    = (const float*)d_in[1];   // (48, 1536)    f32
    const float* bias = (const float*)d_in[2];   // (48,)         f32
    float* out  = (float*)d_out;                 // (4,512,512,48) f32
    float* proj = (float*)d_ws;                  // 786 KB in workspace

    gemm_kernel<<<dim3(256), 256, 0, stream>>>(hs, W, proj);
    bcast_kernel<<<dim3(NROWS), 256, 0, stream>>>(proj, bias, out);
}

// Round 15
// 42.483 us; speedup vs baseline: 1.1216x; 1.1216x over previous
//
#include <hip/hip_runtime.h>

typedef float  f32x4  __attribute__((ext_vector_type(4)));
typedef short  bf16x4 __attribute__((ext_vector_type(4)));
typedef short  bf16x8 __attribute__((ext_vector_type(8)));

// Problem dims (fixed by reference): bs=4, L=512, H=768, C=48
#define H_DIM 768
#define C_DIM 48
#define NROWS 2048          // bs * L
#define TWO_H 1536

// MFMA gemm geometry: 256 blocks = 128 rowgroups x 2 halves; 4 waves/block.
#define GBM 16              // rows per block
#define AST 392             // padded bf16 row stride
#define MT_LD 52            // merge tile row stride (f32)

__device__ __forceinline__ unsigned short f2bf(float f) {   // RNE f32->bf16
    unsigned x = __float_as_uint(f);
    return (unsigned short)((x + 0x7fffu + ((x >> 16) & 1u)) >> 16);
}

// ---------------------------------------------------------------------------
// Kernel 1: proj GEMM via MFMA (bf16 inputs, f32 accum) with register-
// prefetch of the second K-half (single global-latency exposure).
//   block(rg, half): rows rg*16..+16, cols half*48..+48; 256 thr = 4 waves.
//   Per half: A[16][384]+B[48][384] bf16 in LDS (50.2 KB); wave w covers
//   k in [w*96, w*96+96): 3 k-steps x 3 col-tiles = 9 mfma_f32_16x16x32_bf16.
//   Frag k-mapping: k = 4*(lane>>4) + (j&3) + 16*(j>>2); C/D per m89.
// ---------------------------------------------------------------------------
__global__ __launch_bounds__(256) void gemm_kernel(const float* __restrict__ hs,
                                                   const float* __restrict__ W,
                                                   float* __restrict__ proj) {
    __shared__ __align__(16) char smem[50176];
    unsigned short* Ab = (unsigned short*)smem;           // [16][392] bf16
    unsigned short* Bb = Ab + GBM * AST;                  // [48][392] bf16
    float*          mt = (float*)smem;                    // [4][16][52] f32 (aliased)

    const int t    = threadIdx.x;
    const int half = blockIdx.x & 1;
    const int rg   = blockIdx.x >> 1;                     // 0..127
    const int row0 = rg * GBM;

    const int w    = t >> 6;                              // wave 0..3
    const int lane = t & 63;
    const int g    = lane >> 4;                           // 0..3
    const int m    = lane & 15;                           // 0..15

    const f32x4* __restrict__ hs4 = reinterpret_cast<const f32x4*>(hs);
    const f32x4* __restrict__ Wv4 = reinterpret_cast<const f32x4*>(W);

    // Per-thread staging indices (constant across halves).
    int a_row[6], a_kf4[6], b_c[18], b_kf4[18];
    #pragma unroll
    for (int q = 0; q < 6; ++q) {
        const int idx = q * 256 + t;
        a_row[q] = idx / 96;  a_kf4[q] = idx % 96;
    }
    #pragma unroll
    for (int q = 0; q < 18; ++q) {
        const int idx = q * 256 + t;
        b_c[q] = idx / 96;    b_kf4[q] = idx % 96;
    }

    f32x4 acc[3];
    #pragma unroll
    for (int tc = 0; tc < 3; ++tc) acc[tc] = (f32x4){0.f, 0.f, 0.f, 0.f};

    f32x4 av[6], bv[18];

    // ---- load half 0 into regs; cvt+write to LDS ----
    #pragma unroll
    for (int q = 0; q < 6; ++q)
        av[q] = hs4[(size_t)(row0 + a_row[q]) * 192 + a_kf4[q]];
    #pragma unroll
    for (int q = 0; q < 18; ++q)
        bv[q] = Wv4[(size_t)b_c[q] * 384 + half * 192 + b_kf4[q]];
    #pragma unroll
    for (int q = 0; q < 6; ++q) {
        bf16x4 p = {(short)f2bf(av[q].x), (short)f2bf(av[q].y),
                    (short)f2bf(av[q].z), (short)f2bf(av[q].w)};
        *reinterpret_cast<bf16x4*>(Ab + a_row[q] * AST + a_kf4[q] * 4) = p;
    }
    #pragma unroll
    for (int q = 0; q < 18; ++q) {
        bf16x4 p = {(short)f2bf(bv[q].x), (short)f2bf(bv[q].y),
                    (short)f2bf(bv[q].z), (short)f2bf(bv[q].w)};
        *reinterpret_cast<bf16x4*>(Bb + b_c[q] * AST + b_kf4[q] * 4) = p;
    }
    __syncthreads();

    // ---- issue half-1 loads NOW (hide latency under half-0 MFMAs) ----
    #pragma unroll
    for (int q = 0; q < 6; ++q)
        av[q] = hs4[(size_t)(row0 + a_row[q]) * 192 + 96 + a_kf4[q]];
    #pragma unroll
    for (int q = 0; q < 18; ++q)
        bv[q] = Wv4[(size_t)b_c[q] * 384 + half * 192 + 96 + b_kf4[q]];

    // ---- compute half 0 ----
    #pragma unroll
    for (int ks = 0; ks < 3; ++ks) {
        const int klo = w * 96 + ks * 32 + 4 * g;
        const bf16x4 alo = *reinterpret_cast<const bf16x4*>(Ab + m * AST + klo);
        const bf16x4 ahi = *reinterpret_cast<const bf16x4*>(Ab + m * AST + klo + 16);
        bf16x8 af;
        #pragma unroll
        for (int i = 0; i < 4; ++i) { af[i] = alo[i]; af[i + 4] = ahi[i]; }
        #pragma unroll
        for (int tc = 0; tc < 3; ++tc) {
            const unsigned short* bp = Bb + (tc * 16 + m) * AST + klo;
            const bf16x4 blo = *reinterpret_cast<const bf16x4*>(bp);
            const bf16x4 bhi = *reinterpret_cast<const bf16x4*>(bp + 16);
            bf16x8 bfr;
            #pragma unroll
            for (int i = 0; i < 4; ++i) { bfr[i] = blo[i]; bfr[i + 4] = bhi[i]; }
            acc[tc] = __builtin_amdgcn_mfma_f32_16x16x32_bf16(af, bfr, acc[tc], 0, 0, 0);
        }
    }
    __syncthreads();   // everyone done reading LDS half 0

    // ---- cvt+write half 1 (loads already in flight) ----
    #pragma unroll
    for (int q = 0; q < 6; ++q) {
        bf16x4 p = {(short)f2bf(av[q].x), (short)f2bf(av[q].y),
                    (short)f2bf(av[q].z), (short)f2bf(av[q].w)};
        *reinterpret_cast<bf16x4*>(Ab + a_row[q] * AST + a_kf4[q] * 4) = p;
    }
    #pragma unroll
    for (int q = 0; q < 18; ++q) {
        bf16x4 p = {(short)f2bf(bv[q].x), (short)f2bf(bv[q].y),
                    (short)f2bf(bv[q].z), (short)f2bf(bv[q].w)};
        *reinterpret_cast<bf16x4*>(Bb + b_c[q] * AST + b_kf4[q] * 4) = p;
    }
    __syncthreads();

    // ---- compute half 1 ----
    #pragma unroll
    for (int ks = 0; ks < 3; ++ks) {
        const int klo = w * 96 + ks * 32 + 4 * g;
        const bf16x4 alo = *reinterpret_cast<const bf16x4*>(Ab + m * AST + klo);
        const bf16x4 ahi = *reinterpret_cast<const bf16x4*>(Ab + m * AST + klo + 16);
        bf16x8 af;
        #pragma unroll
        for (int i = 0; i < 4; ++i) { af[i] = alo[i]; af[i + 4] = ahi[i]; }
        #pragma unroll
        for (int tc = 0; tc < 3; ++tc) {
            const unsigned short* bp = Bb + (tc * 16 + m) * AST + klo;
            const bf16x4 blo = *reinterpret_cast<const bf16x4*>(bp);
            const bf16x4 bhi = *reinterpret_cast<const bf16x4*>(bp + 16);
            bf16x8 bfr;
            #pragma unroll
            for (int i = 0; i < 4; ++i) { bfr[i] = blo[i]; bfr[i + 4] = bhi[i]; }
            acc[tc] = __builtin_amdgcn_mfma_f32_16x16x32_bf16(af, bfr, acc[tc], 0, 0, 0);
        }
    }

    // ---- merge 4 waves' k-partials (mt aliases A/B; all reads done) ----
    __syncthreads();
    #pragma unroll
    for (int tc = 0; tc < 3; ++tc)
        #pragma unroll
        for (int r = 0; r < 4; ++r)
            mt[w * (GBM * MT_LD) + (g * 4 + r) * MT_LD + tc * 16 + m] = acc[tc][r];
    __syncthreads();

    if (t < GBM * 12) {                                   // 192 f32x4 outputs
        const int row = t / 12;
        const int c4  = t % 12;
        f32x4 s = *reinterpret_cast<const f32x4*>(mt + row * MT_LD + c4 * 4);
        #pragma unroll
        for (int ww = 1; ww < 4; ++ww)
            s += *reinterpret_cast<const f32x4*>(mt + ww * (GBM * MT_LD) + row * MT_LD + c4 * 4);
        reinterpret_cast<f32x4*>(proj)[(size_t)half * (NROWS * 12)
                                       + (size_t)(row0 + row) * 12 + c4] = s;
    }
}

// ---------------------------------------------------------------------------
// Kernel 2: out[b,i,j,c] = proj_i[b,i,c] + proj_j[b,j,c] + bias[c]
// R4/R13 version: plain stores (NT stores measured −5 µs regression in R14).
// ---------------------------------------------------------------------------
__global__ __launch_bounds__(256) void bcast_kernel(const float* __restrict__ proj,
                                                    const float* __restrict__ bias,
                                                    float* __restrict__ out) {
    const int gi = blockIdx.x;          // b*512 + i
    const int b  = gi >> 9;

    __shared__ f32x4 rowi[C_DIM / 4];   // proj_i[b,i,:] + bias  (12 f32x4)

    const int t = threadIdx.x;
    if (t < C_DIM / 4) {
        f32x4 pi = reinterpret_cast<const f32x4*>(proj + (size_t)gi * C_DIM)[t];
        f32x4 bb = reinterpret_cast<const f32x4*>(bias)[t];
        rowi[t] = pi + bb;
    }
    __syncthreads();

    const f32x4* __restrict__ pj =
        reinterpret_cast<const f32x4*>(proj + (size_t)NROWS * C_DIM
                                            + (size_t)b * 512 * C_DIM);
    f32x4* __restrict__ o =
        reinterpret_cast<f32x4*>(out) + (size_t)gi * 6144;

    #pragma unroll
    for (int it = 0; it < 24; ++it) {
        const int p  = it * 256 + t;
        o[p] = pj[p] + rowi[p % 12];
    }
}

extern "C" void kernel_launch(void* const* d_in, const int* in_sizes, int n_in,
                              void* d_out, int out_size, void* d_ws, size_t ws_size,
                              hipStream_t stream) {
    const float* hs   = (const float*)d_in[0];   // (4, 512, 768) f32
    const float* W    = (const float*)d_in[1];   // (48, 1536)    f32
    const float* bias = (const float*)d_in[2];   // (48,)         f32
    float* out  = (float*)d_out;                 // (4,512,512,48) f32
    float* proj = (float*)d_ws;                  // 786 KB in workspace

    gemm_kernel<<<dim3(256), 256, 0, stream>>>(hs, W, proj);
    bcast_kernel<<<dim3(NROWS), 256, 0, stream>>>(proj, bias, out);
}